// Round 2
// baseline (547.353 us; speedup 1.0000x reference)
//
#include <hip/hip_runtime.h>
#include <hip/hip_bf16.h>
#include <hip/hip_fp16.h>

// GCN: 2x GCNConv (symmetric norm, self-loops) + linear head.
// N=100000, E=3200000, IN=128, HID=64, LAB=121.
//
// R8: chunked-L2 aggregate. R7 confirmed the gather is random-access-wall
// bound: feat2 (12.8 MB) >> 4 MB per-XCD L2 -> ~73% of gathers miss L2 and
// crawl the fabric at ~3.7 TB/s. Fix: feat2 stored chunk-planar [4][N][16]
// (GEMM epilogue writes it directly); aggregate runs 4 feature-chunk passes
// (chunk = slow grid index). Per-chunk table = 3.2 MB -> L2-resident; random
// gathers become 32-B L2 hits. Wave = 4 rows x 8 edge-slots x 2 oct,
// dwordx4 gathers, 3-round shfl slot-tree.
// Retained: two-level dst sort; fp16 feat2; bucket_sort emits row_ptr+dinv;
// self-loop folded as deg+1 + epilogue term; dinv[src] in GEMM rowscale;
// GEMM 4x4 reg tile with b128 LDS reads.

#define IN_DIM 128
#define HID 64
#define N_LAB 121
#define NB_BLK 256        // level-1 blocks (chunks)
#define FCHUNK 16         // features per aggregate chunk pass
#define NCHUNK (HID / FCHUNK)

// ---- generic 3-kernel exclusive scan (used for the M1 = nbuk*NB_BLK counts) ----
__global__ void scan1(const int* __restrict__ in, int* __restrict__ out,
                      int* __restrict__ bsums, int n) {
    __shared__ int s[256];
    int i = blockIdx.x * 256 + threadIdx.x;
    int v = (i < n) ? in[i] : 0;
    s[threadIdx.x] = v;
    __syncthreads();
    for (int off = 1; off < 256; off <<= 1) {
        int t = (threadIdx.x >= off) ? s[threadIdx.x - off] : 0;
        __syncthreads();
        s[threadIdx.x] += t;
        __syncthreads();
    }
    if (i < n) out[i] = s[threadIdx.x] - v;  // exclusive
    if (threadIdx.x == 255) bsums[blockIdx.x] = s[255];
}

__global__ void scan2(int* __restrict__ bsums, int nb) {  // single block, nb <= 512
    __shared__ int s[512];
    int v = (threadIdx.x < nb) ? bsums[threadIdx.x] : 0;
    s[threadIdx.x] = v;
    __syncthreads();
    for (int off = 1; off < 512; off <<= 1) {
        int t = (threadIdx.x >= off) ? s[threadIdx.x - off] : 0;
        __syncthreads();
        s[threadIdx.x] += t;
        __syncthreads();
    }
    if (threadIdx.x < nb) bsums[threadIdx.x] = s[threadIdx.x] - v;  // exclusive
}

__global__ void scan_add(int* __restrict__ out, const int* __restrict__ bsums, int n) {
    int i = blockIdx.x * 256 + threadIdx.x;
    if (i < n) out[i] += bsums[blockIdx.x];
}

// ---- L1 pass A: per-block per-bucket counts ----
__global__ __launch_bounds__(256) void bucket_count(const int* __restrict__ dst,
                                                    int* __restrict__ counts,
                                                    int nbuk, int chunk, int E) {
    extern __shared__ int c[];
    for (int j = threadIdx.x; j < nbuk; j += 256) c[j] = 0;
    __syncthreads();
    int beg = blockIdx.x * chunk;
    int end = min(beg + chunk, E);
    for (int i = beg + threadIdx.x; i < end; i += 256)
        atomicAdd(&c[dst[i] >> 8], 1);
    __syncthreads();
    for (int j = threadIdx.x; j < nbuk; j += 256)
        counts[j * NB_BLK + blockIdx.x] = c[j];
}

// ---- L1 pass B: scatter into private contiguous runs ----
__global__ __launch_bounds__(256) void bucket_scatter(const int* __restrict__ src,
                                                      const int* __restrict__ dst,
                                                      const int* __restrict__ base,
                                                      int* __restrict__ bucketed,
                                                      int nbuk, int chunk, int E) {
    extern __shared__ int c[];
    for (int j = threadIdx.x; j < nbuk; j += 256) c[j] = 0;
    __syncthreads();
    int beg = blockIdx.x * chunk;
    int end = min(beg + chunk, E);
    for (int i = beg + threadIdx.x; i < end; i += 256) {
        int d = dst[i];
        int b = d >> 8;
        int r = atomicAdd(&c[b], 1);
        int pos = base[b * NB_BLK + blockIdx.x] + r;
        bucketed[pos] = ((d & 255) << 17) | src[i];  // src < 2^17
    }
}

// ---- L2: within-bucket sort into final CSR srcs; emits row_ptr + dinv ----
__global__ __launch_bounds__(256) void bucket_sort(const int* __restrict__ bucketed,
                                                   const int* __restrict__ base,
                                                   int* __restrict__ srcs,
                                                   int* __restrict__ row_ptr,
                                                   float* __restrict__ dinv,
                                                   int nbuk, int N, int E) {
    __shared__ int h[256];
    __shared__ int cur[256];
    int b = blockIdx.x;
    int nodeBase = b << 8;
    int s = base[b * NB_BLK];
    int e = (b == nbuk - 1) ? E : base[(b + 1) * NB_BLK];
    h[threadIdx.x] = 0;
    __syncthreads();
    for (int i = s + threadIdx.x; i < e; i += 256)
        atomicAdd(&h[bucketed[i] >> 17], 1);
    __syncthreads();
    int v = h[threadIdx.x];
    for (int off = 1; off < 256; off <<= 1) {  // inclusive Hillis-Steele
        int t = (threadIdx.x >= off) ? h[threadIdx.x - off] : 0;
        __syncthreads();
        h[threadIdx.x] += t;
        __syncthreads();
    }
    int excl = h[threadIdx.x] - v;
    cur[threadIdx.x] = excl;
    int node = nodeBase + threadIdx.x;
    if (node < N) {
        row_ptr[node] = s + excl;
        dinv[node] = rsqrtf((float)v + 1.0f);  // +1 = self loop
    }
    if (b == nbuk - 1 && threadIdx.x == 0) row_ptr[N] = E;
    __syncthreads();
    for (int i = s + threadIdx.x; i < e; i += 256) {
        int p = bucketed[i];
        int d = p >> 17;
        int r = atomicAdd(&cur[d], 1);
        srcs[s + r] = p & 0x1FFFF;
    }
}

// ---- C[M,N] = (A[M,K] @ B[K,N]) * rowscale[r] + bias. LDS-staged, 2D reg tile ----
// 64-row tile. Thread (cg, rg) owns cols 4cg..4cg+3 and rows rg + RG*j.
// Per k-quad: 4 b128 A reads (broadcast across cg) + 4 b128 B reads -> 64 fmaf.
// PLANAR (requires OT=__half, N==64): store chunk-planar [N/16][M][16] fp16
// so the aggregate's per-chunk gather table is contiguous (3.2 MB, L2-fits).
template <int K, int N, typename OT, bool PLANAR>
__global__ __launch_bounds__(256) void gemm_kernel(
        const float* __restrict__ A, const float* __restrict__ B,
        const float* __restrict__ bias, const float* __restrict__ rowscale,
        OT* __restrict__ C, int M) {
    constexpr int ROWS = 64;
    constexpr int NPAD = (N <= 64) ? 64 : 128;
    constexpr int CG = NPAD / 4;     // column groups (16 or 32)
    constexpr int RG = 256 / CG;     // thread rows (16 or 8)
    constexpr int RPT = ROWS / RG;   // rows per thread (4 or 8)
    __shared__ float Bs[K * NPAD];
    __shared__ float As[ROWS * K];

    // stage B (zero-pad cols N..NPAD)
    for (int i = threadIdx.x; i < K * NPAD; i += 256) {
        int c = i & (NPAD - 1);
        int k = i / NPAD;
        Bs[i] = (c < N) ? B[k * N + c] : 0.f;
    }
    // stage A tile (coalesced float4); tail block loads only valid rows
    const int row_base = blockIdx.x * ROWS;
    const float* Ablk = A + (size_t)row_base * K;
    int avail = (M - row_base) * K;
    if (avail > ROWS * K) avail = ROWS * K;
    const int nvec = avail >> 2;  // K % 4 == 0
    const float4* __restrict__ Av = (const float4*)Ablk;
    float4* Asv = (float4*)As;
    for (int i = threadIdx.x; i < nvec; i += 256) Asv[i] = Av[i];
    __syncthreads();

    const int cg = threadIdx.x % CG;
    const int rg = threadIdx.x / CG;

    float acc[RPT][4];
    #pragma unroll
    for (int j = 0; j < RPT; ++j) {
        acc[j][0] = 0.f; acc[j][1] = 0.f; acc[j][2] = 0.f; acc[j][3] = 0.f;
    }

    for (int k = 0; k < K; k += 4) {
        float4 Bq[4];
        #pragma unroll
        for (int kk = 0; kk < 4; ++kk)
            Bq[kk] = *(const float4*)&Bs[(k + kk) * NPAD + cg * 4];
        #pragma unroll
        for (int j = 0; j < RPT; ++j) {
            const float4 Aq = *(const float4*)&As[(rg + RG * j) * K + k];
            #pragma unroll
            for (int c = 0; c < 4; ++c) {
                const float b0 = ((const float*)&Bq[0])[c];
                const float b1 = ((const float*)&Bq[1])[c];
                const float b2 = ((const float*)&Bq[2])[c];
                const float b3 = ((const float*)&Bq[3])[c];
                float a = acc[j][c];
                a = fmaf(Aq.x, b0, a);
                a = fmaf(Aq.y, b1, a);
                a = fmaf(Aq.z, b2, a);
                a = fmaf(Aq.w, b3, a);
                acc[j][c] = a;
            }
        }
    }

    // bias for this thread's 4 cols (guarded for N=121 tail)
    float bv[4];
    #pragma unroll
    for (int c = 0; c < 4; ++c) {
        int col = cg * 4 + c;
        bv[c] = (bias && col < N) ? bias[col] : 0.f;
    }

    #pragma unroll
    for (int j = 0; j < RPT; ++j) {
        const int r = row_base + rg + RG * j;
        if (r >= M) continue;
        const float sc = rowscale ? rowscale[r] : 1.0f;
        float o[4];
        #pragma unroll
        for (int c = 0; c < 4; ++c) o[c] = fmaf(acc[j][c], sc, bv[c]);
        if constexpr (PLANAR) {
            // cols cg*4..cg*4+3 lie in one 16-col plane
            const int plane = (cg * 4) >> 4;
            const int incol = (cg * 4) & 15;
            __half* Cp = (__half*)C + (size_t)plane * ((size_t)M * FCHUNK)
                       + (size_t)r * FCHUNK + incol;
            ((__half2*)Cp)[0] = __floats2half2_rn(o[0], o[1]);
            ((__half2*)Cp)[1] = __floats2half2_rn(o[2], o[3]);
        } else {
            OT* Crow = C + (size_t)r * N;
            if constexpr (sizeof(OT) == 4 && (N % 4 == 0)) {
                *(float4*)&Crow[cg * 4] = make_float4(o[0], o[1], o[2], o[3]);
            } else if constexpr (sizeof(OT) == 2 && (N % 4 == 0)) {
                __half2* p = (__half2*)&Crow[cg * 4];
                p[0] = __floats2half2_rn(o[0], o[1]);
                p[1] = __floats2half2_rn(o[2], o[3]);
            } else {
                #pragma unroll
                for (int c = 0; c < 4; ++c) {
                    int col = cg * 4 + c;
                    if (col < N) Crow[col] = (OT)o[c];
                }
            }
        }
    }
}

// ---- chunked pull aggregation ----
// feat2p is chunk-planar [NCHUNK][N][FCHUNK] fp16. Grid = NCHUNK * bpc blocks,
// chunk is the SLOW index so each XCD's L2 holds ~one 3.2 MB chunk table at a
// time and the random gathers are L2 hits. Wave = 4 rows x 8 edge-slots x
// 2 feature-octets; each lane gathers dwordx4 (8 fp16). 3-round shfl_xor tree
// over slots; slot-0 lane pair stores 64 B of the fp32 output row slice.
// out[r, cf..cf+16) = relu(dinv[r]*(feat2p[c][r] + sum_nbr feat2p[c][s]) + b)
__global__ __launch_bounds__(256) void aggregate_chunked(
        const __half* __restrict__ feat2p, const int* __restrict__ rp,
        const int* __restrict__ srcs, const float* __restrict__ dinv,
        const float* __restrict__ bias, float* __restrict__ out,
        int N, int bpc) {
    const int chunk = blockIdx.x / bpc;
    const int rb    = blockIdx.x % bpc;
    const int lane  = threadIdx.x & 63;
    const int wv    = threadIdx.x >> 6;   // wave in block: 0..3
    const int rloc  = lane >> 4;          // row within wave: 0..3
    const int slot  = (lane >> 1) & 7;    // edge slot: 0..7
    const int oct   = lane & 1;           // feature octet: 0..1
    const int row   = rb * 16 + wv * 4 + rloc;
    const bool rowok = (row < N);

    const __half* fb = feat2p + (size_t)chunk * ((size_t)N * FCHUNK) + oct * 8;

    float acc[8];
    #pragma unroll
    for (int i = 0; i < 8; ++i) acc[i] = 0.f;

    // self-loop term, counted once (slot 0 only)
    if (slot == 0 && rowok) {
        const uint4 q = *(const uint4*)(fb + (size_t)row * FCHUNK);
        const __half2* h = (const __half2*)&q;
        #pragma unroll
        for (int i = 0; i < 4; ++i) {
            const float2 f = __half22float2(h[i]);
            acc[2 * i]     += f.x;
            acc[2 * i + 1] += f.y;
        }
    }

    const int beg = rowok ? rp[row] : 0;
    const int end = rowok ? rp[row + 1] : 0;
    int idx = beg + slot;
    while (__any(idx < end)) {
        if (idx < end) {
            const int s = srcs[idx];
            const uint4 q = *(const uint4*)(fb + (size_t)s * FCHUNK);
            const __half2* h = (const __half2*)&q;
            #pragma unroll
            for (int i = 0; i < 4; ++i) {
                const float2 f = __half22float2(h[i]);
                acc[2 * i]     += f.x;
                acc[2 * i + 1] += f.y;
            }
        }
        idx += 8;
    }

    // reduce across the 8 slots (lane bits 1..3)
    #pragma unroll
    for (int m = 2; m <= 8; m <<= 1) {
        #pragma unroll
        for (int i = 0; i < 8; ++i)
            acc[i] += __shfl_xor(acc[i], m, 64);
    }

    if ((lane & 14) == 0 && rowok) {   // slot == 0 lanes (oct 0 and 1)
        const float sc = dinv[row];
        const int cf = chunk * FCHUNK + oct * 8;
        float o[8];
        #pragma unroll
        for (int i = 0; i < 8; ++i)
            o[i] = fmaxf(fmaf(acc[i], sc, bias[cf + i]), 0.f);
        float4* d4 = (float4*)(out + (size_t)row * HID + cf);
        d4[0] = make_float4(o[0], o[1], o[2], o[3]);
        d4[1] = make_float4(o[4], o[5], o[6], o[7]);
    }
}

extern "C" void kernel_launch(void* const* d_in, const int* in_sizes, int n_in,
                              void* d_out, int out_size, void* d_ws, size_t ws_size,
                              hipStream_t stream) {
    const float* x    = (const float*)d_in[0];
    const int*   ei   = (const int*)d_in[1];
    const float* W1   = (const float*)d_in[2];
    const float* b1   = (const float*)d_in[3];
    const float* W2   = (const float*)d_in[4];
    const float* b2   = (const float*)d_in[5];
    const float* Wout = (const float*)d_in[6];
    const float* bout = (const float*)d_in[7];
    float* out = (float*)d_out;

    const int N = in_sizes[0] / IN_DIM;   // 100000
    const int E = in_sizes[1] / 2;        // 3200000
    const int* srcI = ei;
    const int* dstI = ei + E;

    const int nbuk = (N + 255) >> 8;      // 391 coarse buckets
    const int M1 = nbuk * NB_BLK;         // 100096 count entries
    const int chunk = (E + NB_BLK - 1) / NB_BLK;

    // workspace carve-up
    int*    row_ptr = (int*)d_ws;                   // [N+1]
    float*  dinv    = (float*)(row_ptr + (N + 1));  // [N]
    int*    counts  = (int*)(dinv + N);             // [M1]
    int*    base    = counts + M1;                  // [M1]
    int*    bsums2  = base + M1;                    // [512]
    int*    srcs    = bsums2 + 512;                 // [E]
    // feat2 must be 16-B aligned (dwordx4 gathers in aggregate)
    __half* feat2   = (__half*)(((uintptr_t)(srcs + E) + 15) & ~(uintptr_t)15);
    float*  hbuf    = (float*)(feat2 + (size_t)N * HID);  // [N, HID] fp32
    int*    bucketed = (int*)feat2;                 // [E] ints, aliases feat2 (dead until GEMM1)

    const int nbM = (M1 + 255) / 256;               // 391
    const int gemmBlocks = (N + 63) / 64;
    const int bpc = (N + 15) / 16;                  // blocks per chunk pass
    const int aggBlocks = NCHUNK * bpc;
    const size_t ldsBuk = (size_t)nbuk * sizeof(int);

    // ---- two-level sort: edges grouped by dst into srcs; emits row_ptr+dinv ----
    bucket_count<<<NB_BLK, 256, ldsBuk, stream>>>(dstI, counts, nbuk, chunk, E);
    scan1<<<nbM, 256, 0, stream>>>(counts, base, bsums2, M1);
    scan2<<<1, 512, 0, stream>>>(bsums2, nbM);
    scan_add<<<nbM, 256, 0, stream>>>(base, bsums2, M1);
    bucket_scatter<<<NB_BLK, 256, ldsBuk, stream>>>(srcI, dstI, base, bucketed, nbuk, chunk, E);
    bucket_sort<<<nbuk, 256, 0, stream>>>(bucketed, base, srcs, row_ptr, dinv, nbuk, N, E);

    // ---- layer 1 ----
    gemm_kernel<IN_DIM, HID, __half, true><<<gemmBlocks, 256, 0, stream>>>(x, W1, nullptr, dinv, feat2, N);
    aggregate_chunked<<<aggBlocks, 256, 0, stream>>>(feat2, row_ptr, srcs, dinv, b1, hbuf, N, bpc);

    // ---- layer 2 ----
    gemm_kernel<HID, HID, __half, true><<<gemmBlocks, 256, 0, stream>>>(hbuf, W2, nullptr, dinv, feat2, N);
    aggregate_chunked<<<aggBlocks, 256, 0, stream>>>(feat2, row_ptr, srcs, dinv, b2, hbuf, N, bpc);

    // ---- head ----
    gemm_kernel<HID, N_LAB, float, false><<<gemmBlocks, 256, 0, stream>>>(hbuf, Wout, bout, nullptr, out, N);
}

// Round 3
// 533.618 us; speedup vs baseline: 1.0257x; 1.0257x over previous
//
#include <hip/hip_runtime.h>
#include <hip/hip_bf16.h>
#include <hip/hip_fp16.h>

// GCN: 2x GCNConv (symmetric norm, self-loops) + linear head.
// N=100000, E=3200000, IN=128, HID=64, LAB=121.
//
// R9: chunked aggregate kept (R8's L2-residency verified: FETCH 298->117 MB)
// but inner loop rebuilt for issue+MLP: R8 was latency-bound at ~5 cy/visit
// with ~2 loads/wave in flight (7.6 TB/s L2-line ceiling hit). Now: dual
// predicated gathers per iteration (2 srcs + 2 dwordx4 in flight, cndmask
// dword-masking instead of branches), srcs pre-scaled to byte offsets in
// bucket_sort (no per-gather shift), shared f0+f1 adds.
// Retained: chunk-planar feat2 [4][N][16] fp16 (GEMM writes it directly);
// two-level dst sort; bucket_sort emits row_ptr+dinv; self-loop folded as
// deg+1 + epilogue term; dinv[src] in GEMM rowscale; GEMM 4x4 reg tile.

#define IN_DIM 128
#define HID 64
#define N_LAB 121
#define NB_BLK 256        // level-1 blocks (chunks)
#define FCHUNK 16         // features per aggregate chunk pass
#define NCHUNK (HID / FCHUNK)

// ---- generic 3-kernel exclusive scan (used for the M1 = nbuk*NB_BLK counts) ----
__global__ void scan1(const int* __restrict__ in, int* __restrict__ out,
                      int* __restrict__ bsums, int n) {
    __shared__ int s[256];
    int i = blockIdx.x * 256 + threadIdx.x;
    int v = (i < n) ? in[i] : 0;
    s[threadIdx.x] = v;
    __syncthreads();
    for (int off = 1; off < 256; off <<= 1) {
        int t = (threadIdx.x >= off) ? s[threadIdx.x - off] : 0;
        __syncthreads();
        s[threadIdx.x] += t;
        __syncthreads();
    }
    if (i < n) out[i] = s[threadIdx.x] - v;  // exclusive
    if (threadIdx.x == 255) bsums[blockIdx.x] = s[255];
}

__global__ void scan2(int* __restrict__ bsums, int nb) {  // single block, nb <= 512
    __shared__ int s[512];
    int v = (threadIdx.x < nb) ? bsums[threadIdx.x] : 0;
    s[threadIdx.x] = v;
    __syncthreads();
    for (int off = 1; off < 512; off <<= 1) {
        int t = (threadIdx.x >= off) ? s[threadIdx.x - off] : 0;
        __syncthreads();
        s[threadIdx.x] += t;
        __syncthreads();
    }
    if (threadIdx.x < nb) bsums[threadIdx.x] = s[threadIdx.x] - v;  // exclusive
}

__global__ void scan_add(int* __restrict__ out, const int* __restrict__ bsums, int n) {
    int i = blockIdx.x * 256 + threadIdx.x;
    if (i < n) out[i] += bsums[blockIdx.x];
}

// ---- L1 pass A: per-block per-bucket counts ----
__global__ __launch_bounds__(256) void bucket_count(const int* __restrict__ dst,
                                                    int* __restrict__ counts,
                                                    int nbuk, int chunk, int E) {
    extern __shared__ int c[];
    for (int j = threadIdx.x; j < nbuk; j += 256) c[j] = 0;
    __syncthreads();
    int beg = blockIdx.x * chunk;
    int end = min(beg + chunk, E);
    for (int i = beg + threadIdx.x; i < end; i += 256)
        atomicAdd(&c[dst[i] >> 8], 1);
    __syncthreads();
    for (int j = threadIdx.x; j < nbuk; j += 256)
        counts[j * NB_BLK + blockIdx.x] = c[j];
}

// ---- L1 pass B: scatter into private contiguous runs ----
__global__ __launch_bounds__(256) void bucket_scatter(const int* __restrict__ src,
                                                      const int* __restrict__ dst,
                                                      const int* __restrict__ base,
                                                      int* __restrict__ bucketed,
                                                      int nbuk, int chunk, int E) {
    extern __shared__ int c[];
    for (int j = threadIdx.x; j < nbuk; j += 256) c[j] = 0;
    __syncthreads();
    int beg = blockIdx.x * chunk;
    int end = min(beg + chunk, E);
    for (int i = beg + threadIdx.x; i < end; i += 256) {
        int d = dst[i];
        int b = d >> 8;
        int r = atomicAdd(&c[b], 1);
        int pos = base[b * NB_BLK + blockIdx.x] + r;
        bucketed[pos] = ((d & 255) << 17) | src[i];  // src < 2^17
    }
}

// ---- L2: within-bucket sort into final CSR srcs; emits row_ptr + dinv ----
// srcs entries are PRE-SCALED byte offsets (src << 5 = src * FCHUNK * 2B)
// so the aggregate gather needs no per-visit shift.
__global__ __launch_bounds__(256) void bucket_sort(const int* __restrict__ bucketed,
                                                   const int* __restrict__ base,
                                                   int* __restrict__ srcs,
                                                   int* __restrict__ row_ptr,
                                                   float* __restrict__ dinv,
                                                   int nbuk, int N, int E) {
    __shared__ int h[256];
    __shared__ int cur[256];
    int b = blockIdx.x;
    int nodeBase = b << 8;
    int s = base[b * NB_BLK];
    int e = (b == nbuk - 1) ? E : base[(b + 1) * NB_BLK];
    h[threadIdx.x] = 0;
    __syncthreads();
    for (int i = s + threadIdx.x; i < e; i += 256)
        atomicAdd(&h[bucketed[i] >> 17], 1);
    __syncthreads();
    int v = h[threadIdx.x];
    for (int off = 1; off < 256; off <<= 1) {  // inclusive Hillis-Steele
        int t = (threadIdx.x >= off) ? h[threadIdx.x - off] : 0;
        __syncthreads();
        h[threadIdx.x] += t;
        __syncthreads();
    }
    int excl = h[threadIdx.x] - v;
    cur[threadIdx.x] = excl;
    int node = nodeBase + threadIdx.x;
    if (node < N) {
        row_ptr[node] = s + excl;
        dinv[node] = rsqrtf((float)v + 1.0f);  // +1 = self loop
    }
    if (b == nbuk - 1 && threadIdx.x == 0) row_ptr[N] = E;
    __syncthreads();
    for (int i = s + threadIdx.x; i < e; i += 256) {
        int p = bucketed[i];
        int d = p >> 17;
        int r = atomicAdd(&cur[d], 1);
        srcs[s + r] = (p & 0x1FFFF) << 5;   // byte offset into chunk plane
    }
}

// ---- C[M,N] = (A[M,K] @ B[K,N]) * rowscale[r] + bias. LDS-staged, 2D reg tile ----
// 64-row tile. Thread (cg, rg) owns cols 4cg..4cg+3 and rows rg + RG*j.
// Per k-quad: 4 b128 A reads (broadcast across cg) + 4 b128 B reads -> 64 fmaf.
// PLANAR (requires OT=__half, N==64): store chunk-planar [N/16][M][16] fp16
// so the aggregate's per-chunk gather table is contiguous (3.2 MB, L2-fits).
template <int K, int N, typename OT, bool PLANAR>
__global__ __launch_bounds__(256) void gemm_kernel(
        const float* __restrict__ A, const float* __restrict__ B,
        const float* __restrict__ bias, const float* __restrict__ rowscale,
        OT* __restrict__ C, int M) {
    constexpr int ROWS = 64;
    constexpr int NPAD = (N <= 64) ? 64 : 128;
    constexpr int CG = NPAD / 4;     // column groups (16 or 32)
    constexpr int RG = 256 / CG;     // thread rows (16 or 8)
    constexpr int RPT = ROWS / RG;   // rows per thread (4 or 8)
    __shared__ float Bs[K * NPAD];
    __shared__ float As[ROWS * K];

    // stage B (zero-pad cols N..NPAD)
    for (int i = threadIdx.x; i < K * NPAD; i += 256) {
        int c = i & (NPAD - 1);
        int k = i / NPAD;
        Bs[i] = (c < N) ? B[k * N + c] : 0.f;
    }
    // stage A tile (coalesced float4); tail block loads only valid rows
    const int row_base = blockIdx.x * ROWS;
    const float* Ablk = A + (size_t)row_base * K;
    int avail = (M - row_base) * K;
    if (avail > ROWS * K) avail = ROWS * K;
    const int nvec = avail >> 2;  // K % 4 == 0
    const float4* __restrict__ Av = (const float4*)Ablk;
    float4* Asv = (float4*)As;
    for (int i = threadIdx.x; i < nvec; i += 256) Asv[i] = Av[i];
    __syncthreads();

    const int cg = threadIdx.x % CG;
    const int rg = threadIdx.x / CG;

    float acc[RPT][4];
    #pragma unroll
    for (int j = 0; j < RPT; ++j) {
        acc[j][0] = 0.f; acc[j][1] = 0.f; acc[j][2] = 0.f; acc[j][3] = 0.f;
    }

    for (int k = 0; k < K; k += 4) {
        float4 Bq[4];
        #pragma unroll
        for (int kk = 0; kk < 4; ++kk)
            Bq[kk] = *(const float4*)&Bs[(k + kk) * NPAD + cg * 4];
        #pragma unroll
        for (int j = 0; j < RPT; ++j) {
            const float4 Aq = *(const float4*)&As[(rg + RG * j) * K + k];
            #pragma unroll
            for (int c = 0; c < 4; ++c) {
                const float b0 = ((const float*)&Bq[0])[c];
                const float b1 = ((const float*)&Bq[1])[c];
                const float b2 = ((const float*)&Bq[2])[c];
                const float b3 = ((const float*)&Bq[3])[c];
                float a = acc[j][c];
                a = fmaf(Aq.x, b0, a);
                a = fmaf(Aq.y, b1, a);
                a = fmaf(Aq.z, b2, a);
                a = fmaf(Aq.w, b3, a);
                acc[j][c] = a;
            }
        }
    }

    // bias for this thread's 4 cols (guarded for N=121 tail)
    float bv[4];
    #pragma unroll
    for (int c = 0; c < 4; ++c) {
        int col = cg * 4 + c;
        bv[c] = (bias && col < N) ? bias[col] : 0.f;
    }

    #pragma unroll
    for (int j = 0; j < RPT; ++j) {
        const int r = row_base + rg + RG * j;
        if (r >= M) continue;
        const float sc = rowscale ? rowscale[r] : 1.0f;
        float o[4];
        #pragma unroll
        for (int c = 0; c < 4; ++c) o[c] = fmaf(acc[j][c], sc, bv[c]);
        if constexpr (PLANAR) {
            // cols cg*4..cg*4+3 lie in one 16-col plane
            const int plane = (cg * 4) >> 4;
            const int incol = (cg * 4) & 15;
            __half* Cp = (__half*)C + (size_t)plane * ((size_t)M * FCHUNK)
                       + (size_t)r * FCHUNK + incol;
            ((__half2*)Cp)[0] = __floats2half2_rn(o[0], o[1]);
            ((__half2*)Cp)[1] = __floats2half2_rn(o[2], o[3]);
        } else {
            OT* Crow = C + (size_t)r * N;
            if constexpr (sizeof(OT) == 4 && (N % 4 == 0)) {
                *(float4*)&Crow[cg * 4] = make_float4(o[0], o[1], o[2], o[3]);
            } else if constexpr (sizeof(OT) == 2 && (N % 4 == 0)) {
                __half2* p = (__half2*)&Crow[cg * 4];
                p[0] = __floats2half2_rn(o[0], o[1]);
                p[1] = __floats2half2_rn(o[2], o[3]);
            } else {
                #pragma unroll
                for (int c = 0; c < 4; ++c) {
                    int col = cg * 4 + c;
                    if (col < N) Crow[col] = (OT)o[c];
                }
            }
        }
    }
}

// ---- chunked pull aggregation, dual-issue ----
// feat2p is chunk-planar [NCHUNK][N][FCHUNK] fp16. Grid = NCHUNK * bpc blocks,
// chunk = SLOW index so each XCD's L2 holds one 3.2 MB chunk table at a time.
// Wave = 4 rows x 8 edge-slots x 2 feature-octets. Per iteration each lane
// issues 2 srcs loads + 2 dwordx4 gathers (all 4 in flight); out-of-range
// slots are masked with cndmask on the loaded dwords (no branches). srcs
// holds pre-scaled byte offsets. 3-round shfl_xor slot tree; slot-0 lane
// pair stores 64 B of the fp32 output row slice.
__global__ __launch_bounds__(256) void aggregate_chunked(
        const __half* __restrict__ feat2p, const int* __restrict__ rp,
        const int* __restrict__ srcs, const float* __restrict__ dinv,
        const float* __restrict__ bias, float* __restrict__ out,
        int N, int bpc) {
    const int chunk = blockIdx.x / bpc;
    const int rb    = blockIdx.x % bpc;
    const int lane  = threadIdx.x & 63;
    const int wv    = threadIdx.x >> 6;   // wave in block: 0..3
    const int rloc  = lane >> 4;          // row within wave: 0..3
    const int slot  = (lane >> 1) & 7;    // edge slot: 0..7
    const int oct   = lane & 1;           // feature octet: 0..1
    const int row   = rb * 16 + wv * 4 + rloc;
    const bool rowok = (row < N);

    const char* fbB = (const char*)feat2p
        + (size_t)chunk * ((size_t)N * (FCHUNK * 2)) + oct * 16;

    float acc[8];
    #pragma unroll
    for (int i = 0; i < 8; ++i) acc[i] = 0.f;

    // self-loop term, counted once (slot 0 only)
    if (slot == 0 && rowok) {
        const uint4 q = *(const uint4*)(fbB + ((size_t)row << 5));
        const __half2* h = (const __half2*)&q;
        #pragma unroll
        for (int i = 0; i < 4; ++i) {
            const float2 f = __half22float2(h[i]);
            acc[2 * i]     += f.x;
            acc[2 * i + 1] += f.y;
        }
    }

    const int beg = rowok ? rp[row] : 0;
    const int end = rowok ? rp[row + 1] : 0;
    int idx = beg + slot;
    while (__any(idx < end)) {
        const bool p0 = idx < end;
        const bool p1 = (idx + 8) < end;
        const int i0 = p0 ? idx : 0;          // clamp to valid index
        const int i1 = p1 ? (idx + 8) : 0;
        const int o0 = srcs[i0];              // pre-scaled byte offsets
        const int o1 = srcs[i1];
        uint4 q0 = *(const uint4*)(fbB + o0); // both gathers in flight
        uint4 q1 = *(const uint4*)(fbB + o1);
        if (!p0) { q0.x = 0u; q0.y = 0u; q0.z = 0u; q0.w = 0u; }
        if (!p1) { q1.x = 0u; q1.y = 0u; q1.z = 0u; q1.w = 0u; }
        const __half2* h0 = (const __half2*)&q0;
        const __half2* h1 = (const __half2*)&q1;
        #pragma unroll
        for (int i = 0; i < 4; ++i) {
            const float2 f0 = __half22float2(h0[i]);
            const float2 f1 = __half22float2(h1[i]);
            acc[2 * i]     += f0.x + f1.x;
            acc[2 * i + 1] += f0.y + f1.y;
        }
        idx += 16;
    }

    // reduce across the 8 slots (lane bits 1..3)
    #pragma unroll
    for (int m = 2; m <= 8; m <<= 1) {
        #pragma unroll
        for (int i = 0; i < 8; ++i)
            acc[i] += __shfl_xor(acc[i], m, 64);
    }

    if ((lane & 14) == 0 && rowok) {   // slot == 0 lanes (oct 0 and 1)
        const float sc = dinv[row];
        const int cf = chunk * FCHUNK + oct * 8;
        float o[8];
        #pragma unroll
        for (int i = 0; i < 8; ++i)
            o[i] = fmaxf(fmaf(acc[i], sc, bias[cf + i]), 0.f);
        float4* d4 = (float4*)(out + (size_t)row * HID + cf);
        d4[0] = make_float4(o[0], o[1], o[2], o[3]);
        d4[1] = make_float4(o[4], o[5], o[6], o[7]);
    }
}

extern "C" void kernel_launch(void* const* d_in, const int* in_sizes, int n_in,
                              void* d_out, int out_size, void* d_ws, size_t ws_size,
                              hipStream_t stream) {
    const float* x    = (const float*)d_in[0];
    const int*   ei   = (const int*)d_in[1];
    const float* W1   = (const float*)d_in[2];
    const float* b1   = (const float*)d_in[3];
    const float* W2   = (const float*)d_in[4];
    const float* b2   = (const float*)d_in[5];
    const float* Wout = (const float*)d_in[6];
    const float* bout = (const float*)d_in[7];
    float* out = (float*)d_out;

    const int N = in_sizes[0] / IN_DIM;   // 100000
    const int E = in_sizes[1] / 2;        // 3200000
    const int* srcI = ei;
    const int* dstI = ei + E;

    const int nbuk = (N + 255) >> 8;      // 391 coarse buckets
    const int M1 = nbuk * NB_BLK;         // 100096 count entries
    const int chunk = (E + NB_BLK - 1) / NB_BLK;

    // workspace carve-up
    int*    row_ptr = (int*)d_ws;                   // [N+1]
    float*  dinv    = (float*)(row_ptr + (N + 1));  // [N]
    int*    counts  = (int*)(dinv + N);             // [M1]
    int*    base    = counts + M1;                  // [M1]
    int*    bsums2  = base + M1;                    // [512]
    int*    srcs    = bsums2 + 512;                 // [E]
    // feat2 must be 16-B aligned (dwordx4 gathers in aggregate)
    __half* feat2   = (__half*)(((uintptr_t)(srcs + E) + 15) & ~(uintptr_t)15);
    float*  hbuf    = (float*)(feat2 + (size_t)N * HID);  // [N, HID] fp32
    int*    bucketed = (int*)feat2;                 // [E] ints, aliases feat2 (dead until GEMM1)

    const int nbM = (M1 + 255) / 256;               // 391
    const int gemmBlocks = (N + 63) / 64;
    const int bpc = (N + 15) / 16;                  // blocks per chunk pass
    const int aggBlocks = NCHUNK * bpc;
    const size_t ldsBuk = (size_t)nbuk * sizeof(int);

    // ---- two-level sort: edges grouped by dst into srcs; emits row_ptr+dinv ----
    bucket_count<<<NB_BLK, 256, ldsBuk, stream>>>(dstI, counts, nbuk, chunk, E);
    scan1<<<nbM, 256, 0, stream>>>(counts, base, bsums2, M1);
    scan2<<<1, 512, 0, stream>>>(bsums2, nbM);
    scan_add<<<nbM, 256, 0, stream>>>(base, bsums2, M1);
    bucket_scatter<<<NB_BLK, 256, ldsBuk, stream>>>(srcI, dstI, base, bucketed, nbuk, chunk, E);
    bucket_sort<<<nbuk, 256, 0, stream>>>(bucketed, base, srcs, row_ptr, dinv, nbuk, N, E);

    // ---- layer 1 ----
    gemm_kernel<IN_DIM, HID, __half, true><<<gemmBlocks, 256, 0, stream>>>(x, W1, nullptr, dinv, feat2, N);
    aggregate_chunked<<<aggBlocks, 256, 0, stream>>>(feat2, row_ptr, srcs, dinv, b1, hbuf, N, bpc);

    // ---- layer 2 ----
    gemm_kernel<HID, HID, __half, true><<<gemmBlocks, 256, 0, stream>>>(hbuf, W2, nullptr, dinv, feat2, N);
    aggregate_chunked<<<aggBlocks, 256, 0, stream>>>(feat2, row_ptr, srcs, dinv, b2, hbuf, N, bpc);

    // ---- head ----
    gemm_kernel<HID, N_LAB, float, false><<<gemmBlocks, 256, 0, stream>>>(hbuf, Wout, bout, nullptr, out, N);
}

// Round 5
// 511.319 us; speedup vs baseline: 1.0705x; 1.0436x over previous
//
#include <hip/hip_runtime.h>
#include <hip/hip_bf16.h>
#include <hip/hip_fp16.h>

// GCN: 2x GCNConv (symmetric norm, self-loops) + linear head.
// N=100000, E=3200000, IN=128, HID=64, LAB=121.
//
// R11 = R10 resubmit (R10 bench died to container infra, not the kernel;
// OOB/alignment audit clean). Changes vs R9:
// (1) aggregate reverted to R7 full-row layout (89.6 us proven; chunked =
// 99 us request-rate-limited) plus R9 micro-opts: srcs pre-scaled to byte
// offsets (<<7), branch-free dual predicated gathers. (2) GEMM drops the As
// LDS stage: A read direct from global b128, broadcast across cg group
// (L1-served); LDS 64->32 KB -> 5 blocks/CU on GEMM1 (was 2). (3) Sort
// level-1 NB_BLK 256->512 (2 blocks/CU, halves serialized LDS-atomic
// chains); scan2 widened to 1024.
// Retained: two-level dst sort; fp16 feat2 [N][64]; bucket_sort emits
// row_ptr+dinv; self-loop folded as deg+1 + epilogue term; dinv[src] in
// GEMM rowscale; GEMM 4x4 reg tile, b128 LDS B reads.

#define IN_DIM 128
#define HID 64
#define N_LAB 121
#define NB_BLK 512        // level-1 blocks (chunks)

// ---- generic 3-kernel exclusive scan (used for the M1 = nbuk*NB_BLK counts) ----
__global__ void scan1(const int* __restrict__ in, int* __restrict__ out,
                      int* __restrict__ bsums, int n) {
    __shared__ int s[256];
    int i = blockIdx.x * 256 + threadIdx.x;
    int v = (i < n) ? in[i] : 0;
    s[threadIdx.x] = v;
    __syncthreads();
    for (int off = 1; off < 256; off <<= 1) {
        int t = (threadIdx.x >= off) ? s[threadIdx.x - off] : 0;
        __syncthreads();
        s[threadIdx.x] += t;
        __syncthreads();
    }
    if (i < n) out[i] = s[threadIdx.x] - v;  // exclusive
    if (threadIdx.x == 255) bsums[blockIdx.x] = s[255];
}

__global__ __launch_bounds__(1024) void scan2(int* __restrict__ bsums, int nb) {
    // single block, nb <= 1024
    __shared__ int s[1024];
    int v = (threadIdx.x < (unsigned)nb) ? bsums[threadIdx.x] : 0;
    s[threadIdx.x] = v;
    __syncthreads();
    for (int off = 1; off < 1024; off <<= 1) {
        int t = (threadIdx.x >= off) ? s[threadIdx.x - off] : 0;
        __syncthreads();
        s[threadIdx.x] += t;
        __syncthreads();
    }
    if (threadIdx.x < (unsigned)nb) bsums[threadIdx.x] = s[threadIdx.x] - v;  // exclusive
}

__global__ void scan_add(int* __restrict__ out, const int* __restrict__ bsums, int n) {
    int i = blockIdx.x * 256 + threadIdx.x;
    if (i < n) out[i] += bsums[blockIdx.x];
}

// ---- L1 pass A: per-block per-bucket counts ----
__global__ __launch_bounds__(256) void bucket_count(const int* __restrict__ dst,
                                                    int* __restrict__ counts,
                                                    int nbuk, int chunk, int E) {
    extern __shared__ int c[];
    for (int j = threadIdx.x; j < nbuk; j += 256) c[j] = 0;
    __syncthreads();
    int beg = blockIdx.x * chunk;
    int end = min(beg + chunk, E);
    for (int i = beg + threadIdx.x; i < end; i += 256)
        atomicAdd(&c[dst[i] >> 8], 1);
    __syncthreads();
    for (int j = threadIdx.x; j < nbuk; j += 256)
        counts[j * NB_BLK + blockIdx.x] = c[j];
}

// ---- L1 pass B: scatter into private contiguous runs ----
__global__ __launch_bounds__(256) void bucket_scatter(const int* __restrict__ src,
                                                      const int* __restrict__ dst,
                                                      const int* __restrict__ base,
                                                      int* __restrict__ bucketed,
                                                      int nbuk, int chunk, int E) {
    extern __shared__ int c[];
    for (int j = threadIdx.x; j < nbuk; j += 256) c[j] = 0;
    __syncthreads();
    int beg = blockIdx.x * chunk;
    int end = min(beg + chunk, E);
    for (int i = beg + threadIdx.x; i < end; i += 256) {
        int d = dst[i];
        int b = d >> 8;
        int r = atomicAdd(&c[b], 1);
        int pos = base[b * NB_BLK + blockIdx.x] + r;
        bucketed[pos] = ((d & 255) << 17) | src[i];  // src < 2^17
    }
}

// ---- L2: within-bucket sort into final CSR srcs; emits row_ptr + dinv ----
// srcs entries are PRE-SCALED byte offsets (src << 7 = src * 64 * 2B)
// so the aggregate gather needs no per-visit shift.
__global__ __launch_bounds__(256) void bucket_sort(const int* __restrict__ bucketed,
                                                   const int* __restrict__ base,
                                                   int* __restrict__ srcs,
                                                   int* __restrict__ row_ptr,
                                                   float* __restrict__ dinv,
                                                   int nbuk, int N, int E) {
    __shared__ int h[256];
    __shared__ int cur[256];
    int b = blockIdx.x;
    int nodeBase = b << 8;
    int s = base[b * NB_BLK];
    int e = (b == nbuk - 1) ? E : base[(b + 1) * NB_BLK];
    h[threadIdx.x] = 0;
    __syncthreads();
    for (int i = s + threadIdx.x; i < e; i += 256)
        atomicAdd(&h[bucketed[i] >> 17], 1);
    __syncthreads();
    int v = h[threadIdx.x];
    for (int off = 1; off < 256; off <<= 1) {  // inclusive Hillis-Steele
        int t = (threadIdx.x >= off) ? h[threadIdx.x - off] : 0;
        __syncthreads();
        h[threadIdx.x] += t;
        __syncthreads();
    }
    int excl = h[threadIdx.x] - v;
    cur[threadIdx.x] = excl;
    int node = nodeBase + threadIdx.x;
    if (node < N) {
        row_ptr[node] = s + excl;
        dinv[node] = rsqrtf((float)v + 1.0f);  // +1 = self loop
    }
    if (b == nbuk - 1 && threadIdx.x == 0) row_ptr[N] = E;
    __syncthreads();
    for (int i = s + threadIdx.x; i < e; i += 256) {
        int p = bucketed[i];
        int d = p >> 17;
        int r = atomicAdd(&cur[d], 1);
        srcs[s + r] = (p & 0x1FFFF) << 7;   // byte offset into feat2 row
    }
}

// ---- C[M,N] = (A[M,K] @ B[K,N]) * rowscale[r] + bias. B in LDS, A direct ----
// 64-row tile. Thread (cg, rg) owns cols 4cg..4cg+3 and rows rg + RG*j.
// Per k-quad: RPT b128 global A reads (broadcast across the cg group, 4
// distinct addrs/instr, L1-served) + 4 b128 LDS B reads -> 16*RPT fmaf.
template <int K, int N, typename OT>
__global__ __launch_bounds__(256) void gemm_kernel(
        const float* __restrict__ A, const float* __restrict__ B,
        const float* __restrict__ bias, const float* __restrict__ rowscale,
        OT* __restrict__ C, int M) {
    constexpr int ROWS = 64;
    constexpr int NPAD = (N <= 64) ? 64 : 128;
    constexpr int CG = NPAD / 4;     // column groups (16 or 32)
    constexpr int RG = 256 / CG;     // thread rows (16 or 8)
    constexpr int RPT = ROWS / RG;   // rows per thread (4 or 8)
    __shared__ float Bs[K * NPAD];

    // stage B (zero-pad cols N..NPAD)
    for (int i = threadIdx.x; i < K * NPAD; i += 256) {
        int c = i & (NPAD - 1);
        int k = i / NPAD;
        Bs[i] = (c < N) ? B[k * N + c] : 0.f;
    }
    __syncthreads();

    const int cg = threadIdx.x % CG;
    const int rg = threadIdx.x / CG;
    const int row_base = blockIdx.x * ROWS;

    // per-thread row pointers (tail rows clamped; results discarded at store)
    const float* Arow[RPT];
    #pragma unroll
    for (int j = 0; j < RPT; ++j) {
        int r = row_base + rg + RG * j;
        if (r > M - 1) r = M - 1;
        Arow[j] = A + (size_t)r * K;
    }

    float acc[RPT][4];
    #pragma unroll
    for (int j = 0; j < RPT; ++j) {
        acc[j][0] = 0.f; acc[j][1] = 0.f; acc[j][2] = 0.f; acc[j][3] = 0.f;
    }

    for (int k = 0; k < K; k += 4) {
        float4 Bq[4];
        #pragma unroll
        for (int kk = 0; kk < 4; ++kk)
            Bq[kk] = *(const float4*)&Bs[(k + kk) * NPAD + cg * 4];
        #pragma unroll
        for (int j = 0; j < RPT; ++j) {
            const float4 Aq = *(const float4*)(Arow[j] + k);
            #pragma unroll
            for (int c = 0; c < 4; ++c) {
                const float b0 = ((const float*)&Bq[0])[c];
                const float b1 = ((const float*)&Bq[1])[c];
                const float b2 = ((const float*)&Bq[2])[c];
                const float b3 = ((const float*)&Bq[3])[c];
                float a = acc[j][c];
                a = fmaf(Aq.x, b0, a);
                a = fmaf(Aq.y, b1, a);
                a = fmaf(Aq.z, b2, a);
                a = fmaf(Aq.w, b3, a);
                acc[j][c] = a;
            }
        }
    }

    // bias for this thread's 4 cols (guarded for N=121 tail)
    float bv[4];
    #pragma unroll
    for (int c = 0; c < 4; ++c) {
        int col = cg * 4 + c;
        bv[c] = (bias && col < N) ? bias[col] : 0.f;
    }

    #pragma unroll
    for (int j = 0; j < RPT; ++j) {
        const int r = row_base + rg + RG * j;
        if (r >= M) continue;
        const float sc = rowscale ? rowscale[r] : 1.0f;
        float o[4];
        #pragma unroll
        for (int c = 0; c < 4; ++c) o[c] = fmaf(acc[j][c], sc, bv[c]);
        OT* Crow = C + (size_t)r * N;
        if constexpr (sizeof(OT) == 4 && (N % 4 == 0)) {
            *(float4*)&Crow[cg * 4] = make_float4(o[0], o[1], o[2], o[3]);
        } else if constexpr (sizeof(OT) == 2 && (N % 4 == 0)) {
            __half2* p = (__half2*)&Crow[cg * 4];
            p[0] = __floats2half2_rn(o[0], o[1]);
            p[1] = __floats2half2_rn(o[2], o[3]);
        } else {
            #pragma unroll
            for (int c = 0; c < 4; ++c) {
                int col = cg * 4 + c;
                if (col < N) Crow[col] = (OT)o[c];
            }
        }
    }
}

// ---- pull aggregation: one wave per dst row (R7 layout) ----
// Lanes = 8 edge-slots x 8 feature-octets; each lane gathers dwordx4 (8 fp16,
// 16 B): one load instr = 8 edges = 1 KB. Dual predicated gathers per
// iteration (branch-free). srcs holds pre-scaled byte offsets (src*128).
// fp32 accum; 3-round shfl_xor slot tree; slot-0 lanes store 2x float4.
// out[r] = relu(dinv[r] * (feat2[r] + sum_{s in N_in(r)} feat2[s]) + bias)
__global__ __launch_bounds__(256) void aggregate(
        const __half* __restrict__ feat2, const int* __restrict__ rp,
        const int* __restrict__ srcs, const float* __restrict__ dinv,
        const float* __restrict__ bias, float* __restrict__ out, int N) {
    const int wid = (int)((((size_t)blockIdx.x * 256) + threadIdx.x) >> 6);
    if (wid >= N) return;  // wave-uniform
    const int lane = threadIdx.x & 63;
    const int slot = lane >> 3;          // 0..7 edge slot
    const int oct  = lane & 7;           // feature octet
    const char* fbB = (const char*)feat2 + oct * 16;

    float acc[8];
    #pragma unroll
    for (int i = 0; i < 8; ++i) acc[i] = 0.f;

    // self-loop term: slot 0 loads own row's octet (counted once after tree)
    if (slot == 0) {
        const uint4 q = *(const uint4*)(fbB + ((size_t)wid << 7));
        const __half2* h = (const __half2*)&q;
        #pragma unroll
        for (int i = 0; i < 4; ++i) {
            const float2 f = __half22float2(h[i]);
            acc[2 * i]     += f.x;
            acc[2 * i + 1] += f.y;
        }
    }

    const int beg = rp[wid], end = rp[wid + 1];
    int idx = beg + slot;
    while (__any(idx < end)) {
        const bool p0 = idx < end;
        const bool p1 = (idx + 8) < end;
        const int i0 = p0 ? idx : beg;        // clamp to a valid index
        const int i1 = p1 ? (idx + 8) : beg;
        const int o0 = srcs[i0];              // pre-scaled byte offsets
        const int o1 = srcs[i1];
        uint4 q0 = *(const uint4*)(fbB + o0); // both gathers in flight
        uint4 q1 = *(const uint4*)(fbB + o1);
        if (!p0) { q0.x = 0u; q0.y = 0u; q0.z = 0u; q0.w = 0u; }
        if (!p1) { q1.x = 0u; q1.y = 0u; q1.z = 0u; q1.w = 0u; }
        const __half2* h0 = (const __half2*)&q0;
        const __half2* h1 = (const __half2*)&q1;
        #pragma unroll
        for (int i = 0; i < 4; ++i) {
            const float2 f0 = __half22float2(h0[i]);
            const float2 f1 = __half22float2(h1[i]);
            acc[2 * i]     += f0.x + f1.x;
            acc[2 * i + 1] += f0.y + f1.y;
        }
        idx += 16;
    }

    // reduce across the 8 slots (lane bits 3..5)
    #pragma unroll
    for (int m = 8; m <= 32; m <<= 1) {
        #pragma unroll
        for (int i = 0; i < 8; ++i)
            acc[i] += __shfl_xor(acc[i], m, 64);
    }

    if (slot == 0) {
        const float sc = dinv[wid];
        float o[8];
        #pragma unroll
        for (int i = 0; i < 8; ++i)
            o[i] = fmaxf(fmaf(acc[i], sc, bias[oct * 8 + i]), 0.f);
        float4* d4 = (float4*)(out + (((size_t)wid << 6) + oct * 8));
        d4[0] = make_float4(o[0], o[1], o[2], o[3]);
        d4[1] = make_float4(o[4], o[5], o[6], o[7]);
    }
}

extern "C" void kernel_launch(void* const* d_in, const int* in_sizes, int n_in,
                              void* d_out, int out_size, void* d_ws, size_t ws_size,
                              hipStream_t stream) {
    const float* x    = (const float*)d_in[0];
    const int*   ei   = (const int*)d_in[1];
    const float* W1   = (const float*)d_in[2];
    const float* b1   = (const float*)d_in[3];
    const float* W2   = (const float*)d_in[4];
    const float* b2   = (const float*)d_in[5];
    const float* Wout = (const float*)d_in[6];
    const float* bout = (const float*)d_in[7];
    float* out = (float*)d_out;

    const int N = in_sizes[0] / IN_DIM;   // 100000
    const int E = in_sizes[1] / 2;        // 3200000
    const int* srcI = ei;
    const int* dstI = ei + E;

    const int nbuk = (N + 255) >> 8;      // 391 coarse buckets
    const int M1 = nbuk * NB_BLK;         // 200192 count entries
    const int chunk = (E + NB_BLK - 1) / NB_BLK;

    // workspace carve-up
    int*    row_ptr = (int*)d_ws;                   // [N+1]
    float*  dinv    = (float*)(row_ptr + (N + 1));  // [N]
    int*    counts  = (int*)(dinv + N);             // [M1]
    int*    base    = counts + M1;                  // [M1]
    int*    bsums2  = base + M1;                    // [1024]
    int*    srcs    = bsums2 + 1024;                // [E]
    // feat2 must be 16-B aligned (dwordx4 gathers in aggregate)
    __half* feat2   = (__half*)(((uintptr_t)(srcs + E) + 15) & ~(uintptr_t)15);
    float*  hbuf    = (float*)(feat2 + (size_t)N * HID);  // [N, HID] fp32
    int*    bucketed = (int*)feat2;                 // [E] ints, aliases feat2 (dead until GEMM1)

    const int nbM = (M1 + 255) / 256;               // 782
    const int gemmBlocks = (N + 63) / 64;
    const int aggBlocks = (int)(((size_t)N * HID + 255) / 256);
    const size_t ldsBuk = (size_t)nbuk * sizeof(int);

    // ---- two-level sort: edges grouped by dst into srcs; emits row_ptr+dinv ----
    bucket_count<<<NB_BLK, 256, ldsBuk, stream>>>(dstI, counts, nbuk, chunk, E);
    scan1<<<nbM, 256, 0, stream>>>(counts, base, bsums2, M1);
    scan2<<<1, 1024, 0, stream>>>(bsums2, nbM);
    scan_add<<<nbM, 256, 0, stream>>>(base, bsums2, M1);
    bucket_scatter<<<NB_BLK, 256, ldsBuk, stream>>>(srcI, dstI, base, bucketed, nbuk, chunk, E);
    bucket_sort<<<nbuk, 256, 0, stream>>>(bucketed, base, srcs, row_ptr, dinv, nbuk, N, E);

    // ---- layer 1 ----
    gemm_kernel<IN_DIM, HID, __half><<<gemmBlocks, 256, 0, stream>>>(x, W1, nullptr, dinv, feat2, N);
    aggregate<<<aggBlocks, 256, 0, stream>>>(feat2, row_ptr, srcs, dinv, b1, hbuf, N);

    // ---- layer 2 ----
    gemm_kernel<HID, HID, __half><<<gemmBlocks, 256, 0, stream>>>(hbuf, W2, nullptr, dinv, feat2, N);
    aggregate<<<aggBlocks, 256, 0, stream>>>(feat2, row_ptr, srcs, dinv, b2, hbuf, N);

    // ---- head ----
    gemm_kernel<HID, N_LAB, float><<<gemmBlocks, 256, 0, stream>>>(hbuf, Wout, bout, nullptr, out, N);
}

// Round 6
// 497.042 us; speedup vs baseline: 1.1012x; 1.0287x over previous
//
#include <hip/hip_runtime.h>
#include <hip/hip_bf16.h>
#include <hip/hip_fp16.h>

// GCN: 2x GCNConv (symmetric norm, self-loops) + linear head.
// N=100000, E=3200000, IN=128, HID=64, LAB=121.
//
// R12: non-aggregate pool (333 us). (1) scan_add kernel removed: bsums2
// offset folded into bucket_scatter (LDS-cached per-block bases, also kills
// the per-edge base[] global re-read) and bucket_sort boundary reads.
// (2) GEMM ROWS 64->128 for gemm1/gemm2 (RPT=8): 128 fma per 12 mem-instr
// per k-quad (was 64:8), half the blocks/B-staging. (3) int2-vectorized
// edge streaming in bucket_count/scatter.
// Aggregate FROZEN at R11 form: R7-R11 showed all variants pin at ~0.47
// divergent 16-B requests/cy/CU (~89 us) regardless of L2 residency or MLP
// -> request-processing wall; no dtype headroom (absmax at threshold).
// Retained: two-level dst sort; fp16 feat2 [N][64]; bucket_sort emits
// row_ptr+dinv; self-loop folded as deg+1 + epilogue term; dinv[src] in
// GEMM rowscale; srcs pre-scaled byte offsets (<<7).

#define IN_DIM 128
#define HID 64
#define N_LAB 121
#define NB_BLK 512        // level-1 blocks (chunks)

// ---- scan pass 1: 256-wide block scans (produces local-exclusive + sums) ----
__global__ void scan1(const int* __restrict__ in, int* __restrict__ out,
                      int* __restrict__ bsums, int n) {
    __shared__ int s[256];
    int i = blockIdx.x * 256 + threadIdx.x;
    int v = (i < n) ? in[i] : 0;
    s[threadIdx.x] = v;
    __syncthreads();
    for (int off = 1; off < 256; off <<= 1) {
        int t = (threadIdx.x >= off) ? s[threadIdx.x - off] : 0;
        __syncthreads();
        s[threadIdx.x] += t;
        __syncthreads();
    }
    if (i < n) out[i] = s[threadIdx.x] - v;  // exclusive within block
    if (threadIdx.x == 255) bsums[blockIdx.x] = s[255];
}

__global__ __launch_bounds__(1024) void scan2(int* __restrict__ bsums, int nb) {
    // single block, nb <= 1024
    __shared__ int s[1024];
    int v = (threadIdx.x < (unsigned)nb) ? bsums[threadIdx.x] : 0;
    s[threadIdx.x] = v;
    __syncthreads();
    for (int off = 1; off < 1024; off <<= 1) {
        int t = (threadIdx.x >= off) ? s[threadIdx.x - off] : 0;
        __syncthreads();
        s[threadIdx.x] += t;
        __syncthreads();
    }
    if (threadIdx.x < (unsigned)nb) bsums[threadIdx.x] = s[threadIdx.x] - v;  // exclusive
}

// ---- L1 pass A: per-block per-bucket counts (int2 streaming) ----
__global__ __launch_bounds__(256) void bucket_count(const int* __restrict__ dst,
                                                    int* __restrict__ counts,
                                                    int nbuk, int chunk, int E) {
    extern __shared__ int c[];
    for (int j = threadIdx.x; j < nbuk; j += 256) c[j] = 0;
    __syncthreads();
    int beg = blockIdx.x * chunk;
    int end = min(beg + chunk, E);
    int n = end - beg;
    if (n > 0) {
        const int2* p2 = (const int2*)(dst + beg);   // beg even (chunk even)
        int nPair = n >> 1;
        for (int t = threadIdx.x; t < nPair; t += 256) {
            int2 d = p2[t];
            atomicAdd(&c[d.x >> 8], 1);
            atomicAdd(&c[d.y >> 8], 1);
        }
        if ((n & 1) && threadIdx.x == 0)
            atomicAdd(&c[dst[end - 1] >> 8], 1);
    }
    __syncthreads();
    for (int j = threadIdx.x; j < nbuk; j += 256)
        counts[j * NB_BLK + blockIdx.x] = c[j];
}

// ---- L1 pass B: scatter into private contiguous runs ----
// bases folded with bsums2 (scan_add eliminated) and cached in LDS.
__global__ __launch_bounds__(256) void bucket_scatter(const int* __restrict__ src,
                                                      const int* __restrict__ dst,
                                                      const int* __restrict__ base,
                                                      const int* __restrict__ bsums2,
                                                      int* __restrict__ bucketed,
                                                      int nbuk, int chunk, int E) {
    extern __shared__ int sm[];
    int* c  = sm;          // cursors [nbuk]
    int* bs = sm + nbuk;   // absolute bases [nbuk]
    for (int j = threadIdx.x; j < nbuk; j += 256) {
        c[j] = 0;
        int idx = j * NB_BLK + blockIdx.x;
        bs[j] = base[idx] + bsums2[idx >> 8];
    }
    __syncthreads();
    int beg = blockIdx.x * chunk;
    int end = min(beg + chunk, E);
    int n = end - beg;
    if (n > 0) {
        const int2* d2 = (const int2*)(dst + beg);
        const int2* s2 = (const int2*)(src + beg);
        int nPair = n >> 1;
        for (int t = threadIdx.x; t < nPair; t += 256) {
            int2 d = d2[t];
            int2 s = s2[t];
            int b0 = d.x >> 8;
            int r0 = atomicAdd(&c[b0], 1);
            bucketed[bs[b0] + r0] = ((d.x & 255) << 17) | s.x;  // src < 2^17
            int b1 = d.y >> 8;
            int r1 = atomicAdd(&c[b1], 1);
            bucketed[bs[b1] + r1] = ((d.y & 255) << 17) | s.y;
        }
        if ((n & 1) && threadIdx.x == 0) {
            int d = dst[end - 1];
            int b = d >> 8;
            int r = atomicAdd(&c[b], 1);
            bucketed[bs[b] + r] = ((d & 255) << 17) | src[end - 1];
        }
    }
}

// ---- L2: within-bucket sort into final CSR srcs; emits row_ptr + dinv ----
// srcs entries are PRE-SCALED byte offsets (src << 7 = src * 64 * 2B).
__global__ __launch_bounds__(256) void bucket_sort(const int* __restrict__ bucketed,
                                                   const int* __restrict__ base,
                                                   const int* __restrict__ bsums2,
                                                   int* __restrict__ srcs,
                                                   int* __restrict__ row_ptr,
                                                   float* __restrict__ dinv,
                                                   int nbuk, int N, int E) {
    __shared__ int h[256];
    __shared__ int cur[256];
    int b = blockIdx.x;
    int nodeBase = b << 8;
    int idx0 = b * NB_BLK;
    int s = base[idx0] + bsums2[idx0 >> 8];
    int e;
    if (b == nbuk - 1) {
        e = E;
    } else {
        int idx1 = (b + 1) * NB_BLK;
        e = base[idx1] + bsums2[idx1 >> 8];
    }
    h[threadIdx.x] = 0;
    __syncthreads();
    for (int i = s + threadIdx.x; i < e; i += 256)
        atomicAdd(&h[bucketed[i] >> 17], 1);
    __syncthreads();
    int v = h[threadIdx.x];
    for (int off = 1; off < 256; off <<= 1) {  // inclusive Hillis-Steele
        int t = (threadIdx.x >= off) ? h[threadIdx.x - off] : 0;
        __syncthreads();
        h[threadIdx.x] += t;
        __syncthreads();
    }
    int excl = h[threadIdx.x] - v;
    cur[threadIdx.x] = excl;
    int node = nodeBase + threadIdx.x;
    if (node < N) {
        row_ptr[node] = s + excl;
        dinv[node] = rsqrtf((float)v + 1.0f);  // +1 = self loop
    }
    if (b == nbuk - 1 && threadIdx.x == 0) row_ptr[N] = E;
    __syncthreads();
    for (int i = s + threadIdx.x; i < e; i += 256) {
        int p = bucketed[i];
        int d = p >> 17;
        int r = atomicAdd(&cur[d], 1);
        srcs[s + r] = (p & 0x1FFFF) << 7;   // byte offset into feat2 row
    }
}

// ---- C[M,N] = (A[M,K] @ B[K,N]) * rowscale[r] + bias. B in LDS, A direct ----
// ROWS-row tile. Thread (cg, rg) owns cols 4cg..4cg+3 and rows rg + RG*j.
// Per k-quad: RPT b128 global A reads (broadcast across the cg group,
// L1-served) + 4 b128 LDS B reads -> 16*RPT fmaf.
template <int K, int N, int ROWS, typename OT>
__global__ __launch_bounds__(256) void gemm_kernel(
        const float* __restrict__ A, const float* __restrict__ B,
        const float* __restrict__ bias, const float* __restrict__ rowscale,
        OT* __restrict__ C, int M) {
    constexpr int NPAD = (N <= 64) ? 64 : 128;
    constexpr int CG = NPAD / 4;     // column groups (16 or 32)
    constexpr int RG = 256 / CG;     // thread rows (16 or 8)
    constexpr int RPT = ROWS / RG;   // rows per thread
    __shared__ float Bs[K * NPAD];

    // stage B (zero-pad cols N..NPAD)
    for (int i = threadIdx.x; i < K * NPAD; i += 256) {
        int c = i & (NPAD - 1);
        int k = i / NPAD;
        Bs[i] = (c < N) ? B[k * N + c] : 0.f;
    }
    __syncthreads();

    const int cg = threadIdx.x % CG;
    const int rg = threadIdx.x / CG;
    const int row_base = blockIdx.x * ROWS;

    // per-thread row pointers (tail rows clamped; results discarded at store)
    const float* Arow[RPT];
    #pragma unroll
    for (int j = 0; j < RPT; ++j) {
        int r = row_base + rg + RG * j;
        if (r > M - 1) r = M - 1;
        Arow[j] = A + (size_t)r * K;
    }

    float acc[RPT][4];
    #pragma unroll
    for (int j = 0; j < RPT; ++j) {
        acc[j][0] = 0.f; acc[j][1] = 0.f; acc[j][2] = 0.f; acc[j][3] = 0.f;
    }

    for (int k = 0; k < K; k += 4) {
        float4 Bq[4];
        #pragma unroll
        for (int kk = 0; kk < 4; ++kk)
            Bq[kk] = *(const float4*)&Bs[(k + kk) * NPAD + cg * 4];
        #pragma unroll
        for (int j = 0; j < RPT; ++j) {
            const float4 Aq = *(const float4*)(Arow[j] + k);
            #pragma unroll
            for (int c = 0; c < 4; ++c) {
                const float b0 = ((const float*)&Bq[0])[c];
                const float b1 = ((const float*)&Bq[1])[c];
                const float b2 = ((const float*)&Bq[2])[c];
                const float b3 = ((const float*)&Bq[3])[c];
                float a = acc[j][c];
                a = fmaf(Aq.x, b0, a);
                a = fmaf(Aq.y, b1, a);
                a = fmaf(Aq.z, b2, a);
                a = fmaf(Aq.w, b3, a);
                acc[j][c] = a;
            }
        }
    }

    // bias for this thread's 4 cols (guarded for N=121 tail)
    float bv[4];
    #pragma unroll
    for (int c = 0; c < 4; ++c) {
        int col = cg * 4 + c;
        bv[c] = (bias && col < N) ? bias[col] : 0.f;
    }

    #pragma unroll
    for (int j = 0; j < RPT; ++j) {
        const int r = row_base + rg + RG * j;
        if (r >= M) continue;
        const float sc = rowscale ? rowscale[r] : 1.0f;
        float o[4];
        #pragma unroll
        for (int c = 0; c < 4; ++c) o[c] = fmaf(acc[j][c], sc, bv[c]);
        OT* Crow = C + (size_t)r * N;
        if constexpr (sizeof(OT) == 4 && (N % 4 == 0)) {
            *(float4*)&Crow[cg * 4] = make_float4(o[0], o[1], o[2], o[3]);
        } else if constexpr (sizeof(OT) == 2 && (N % 4 == 0)) {
            __half2* p = (__half2*)&Crow[cg * 4];
            p[0] = __floats2half2_rn(o[0], o[1]);
            p[1] = __floats2half2_rn(o[2], o[3]);
        } else {
            #pragma unroll
            for (int c = 0; c < 4; ++c) {
                int col = cg * 4 + c;
                if (col < N) Crow[col] = (OT)o[c];
            }
        }
    }
}

// ---- pull aggregation: one wave per dst row (FROZEN R11 form) ----
// Lanes = 8 edge-slots x 8 feature-octets; each lane gathers dwordx4 (8 fp16,
// 16 B): one load instr = 8 edges = 1 KB. Dual predicated gathers per
// iteration (branch-free). srcs holds pre-scaled byte offsets (src*128).
// fp32 accum; 3-round shfl_xor slot tree; slot-0 lanes store 2x float4.
// out[r] = relu(dinv[r] * (feat2[r] + sum_{s in N_in(r)} feat2[s]) + bias)
__global__ __launch_bounds__(256) void aggregate(
        const __half* __restrict__ feat2, const int* __restrict__ rp,
        const int* __restrict__ srcs, const float* __restrict__ dinv,
        const float* __restrict__ bias, float* __restrict__ out, int N) {
    const int wid = (int)((((size_t)blockIdx.x * 256) + threadIdx.x) >> 6);
    if (wid >= N) return;  // wave-uniform
    const int lane = threadIdx.x & 63;
    const int slot = lane >> 3;          // 0..7 edge slot
    const int oct  = lane & 7;           // feature octet
    const char* fbB = (const char*)feat2 + oct * 16;

    float acc[8];
    #pragma unroll
    for (int i = 0; i < 8; ++i) acc[i] = 0.f;

    // self-loop term: slot 0 loads own row's octet (counted once after tree)
    if (slot == 0) {
        const uint4 q = *(const uint4*)(fbB + ((size_t)wid << 7));
        const __half2* h = (const __half2*)&q;
        #pragma unroll
        for (int i = 0; i < 4; ++i) {
            const float2 f = __half22float2(h[i]);
            acc[2 * i]     += f.x;
            acc[2 * i + 1] += f.y;
        }
    }

    const int beg = rp[wid], end = rp[wid + 1];
    int idx = beg + slot;
    while (__any(idx < end)) {
        const bool p0 = idx < end;
        const bool p1 = (idx + 8) < end;
        const int i0 = p0 ? idx : beg;        // clamp to a valid index
        const int i1 = p1 ? (idx + 8) : beg;
        const int o0 = srcs[i0];              // pre-scaled byte offsets
        const int o1 = srcs[i1];
        uint4 q0 = *(const uint4*)(fbB + o0); // both gathers in flight
        uint4 q1 = *(const uint4*)(fbB + o1);
        if (!p0) { q0.x = 0u; q0.y = 0u; q0.z = 0u; q0.w = 0u; }
        if (!p1) { q1.x = 0u; q1.y = 0u; q1.z = 0u; q1.w = 0u; }
        const __half2* h0 = (const __half2*)&q0;
        const __half2* h1 = (const __half2*)&q1;
        #pragma unroll
        for (int i = 0; i < 4; ++i) {
            const float2 f0 = __half22float2(h0[i]);
            const float2 f1 = __half22float2(h1[i]);
            acc[2 * i]     += f0.x + f1.x;
            acc[2 * i + 1] += f0.y + f1.y;
        }
        idx += 16;
    }

    // reduce across the 8 slots (lane bits 3..5)
    #pragma unroll
    for (int m = 8; m <= 32; m <<= 1) {
        #pragma unroll
        for (int i = 0; i < 8; ++i)
            acc[i] += __shfl_xor(acc[i], m, 64);
    }

    if (slot == 0) {
        const float sc = dinv[wid];
        float o[8];
        #pragma unroll
        for (int i = 0; i < 8; ++i)
            o[i] = fmaxf(fmaf(acc[i], sc, bias[oct * 8 + i]), 0.f);
        float4* d4 = (float4*)(out + (((size_t)wid << 6) + oct * 8));
        d4[0] = make_float4(o[0], o[1], o[2], o[3]);
        d4[1] = make_float4(o[4], o[5], o[6], o[7]);
    }
}

extern "C" void kernel_launch(void* const* d_in, const int* in_sizes, int n_in,
                              void* d_out, int out_size, void* d_ws, size_t ws_size,
                              hipStream_t stream) {
    const float* x    = (const float*)d_in[0];
    const int*   ei   = (const int*)d_in[1];
    const float* W1   = (const float*)d_in[2];
    const float* b1   = (const float*)d_in[3];
    const float* W2   = (const float*)d_in[4];
    const float* b2   = (const float*)d_in[5];
    const float* Wout = (const float*)d_in[6];
    const float* bout = (const float*)d_in[7];
    float* out = (float*)d_out;

    const int N = in_sizes[0] / IN_DIM;   // 100000
    const int E = in_sizes[1] / 2;        // 3200000
    const int* srcI = ei;
    const int* dstI = ei + E;

    const int nbuk = (N + 255) >> 8;      // 391 coarse buckets
    const int M1 = nbuk * NB_BLK;         // 200192 count entries
    const int chunk = (E + NB_BLK - 1) / NB_BLK;

    // workspace carve-up
    int*    row_ptr = (int*)d_ws;                   // [N+1]
    float*  dinv    = (float*)(row_ptr + (N + 1));  // [N]
    int*    counts  = (int*)(dinv + N);             // [M1]
    int*    base    = counts + M1;                  // [M1]
    int*    bsums2  = base + M1;                    // [1024]
    int*    srcs    = bsums2 + 1024;                // [E]
    // feat2 must be 16-B aligned (dwordx4 gathers in aggregate)
    __half* feat2   = (__half*)(((uintptr_t)(srcs + E) + 15) & ~(uintptr_t)15);
    float*  hbuf    = (float*)(feat2 + (size_t)N * HID);  // [N, HID] fp32
    int*    bucketed = (int*)feat2;                 // [E] ints, aliases feat2 (dead until GEMM1)

    const int nbM = (M1 + 255) / 256;               // 782
    const int gemmBlocks128 = (N + 127) / 128;      // 782
    const int gemmBlocks64  = (N + 63) / 64;        // 1563
    const int aggBlocks = (int)(((size_t)N * HID + 255) / 256);
    const size_t ldsBuk = (size_t)nbuk * sizeof(int);

    // ---- two-level sort: edges grouped by dst into srcs; emits row_ptr+dinv ----
    bucket_count<<<NB_BLK, 256, ldsBuk, stream>>>(dstI, counts, nbuk, chunk, E);
    scan1<<<nbM, 256, 0, stream>>>(counts, base, bsums2, M1);
    scan2<<<1, 1024, 0, stream>>>(bsums2, nbM);
    bucket_scatter<<<NB_BLK, 256, 2 * ldsBuk, stream>>>(srcI, dstI, base, bsums2,
                                                        bucketed, nbuk, chunk, E);
    bucket_sort<<<nbuk, 256, 0, stream>>>(bucketed, base, bsums2, srcs, row_ptr,
                                          dinv, nbuk, N, E);

    // ---- layer 1 ----
    gemm_kernel<IN_DIM, HID, 128, __half><<<gemmBlocks128, 256, 0, stream>>>(
        x, W1, nullptr, dinv, feat2, N);
    aggregate<<<aggBlocks, 256, 0, stream>>>(feat2, row_ptr, srcs, dinv, b1, hbuf, N);

    // ---- layer 2 ----
    gemm_kernel<HID, HID, 128, __half><<<gemmBlocks128, 256, 0, stream>>>(
        hbuf, W2, nullptr, dinv, feat2, N);
    aggregate<<<aggBlocks, 256, 0, stream>>>(feat2, row_ptr, srcs, dinv, b2, hbuf, N);

    // ---- head ----
    gemm_kernel<HID, N_LAB, 64, float><<<gemmBlocks64, 256, 0, stream>>>(
        hbuf, Wout, bout, nullptr, out, N);
}